// Round 1
// baseline (190.823 us; speedup 1.0000x reference)
//
#include <hip/hip_runtime.h>
#include <math.h>

#define N_NODES 50000
#define N_EDGES 800000
#define NFEAT 256
#define NHID 64
#define NCLASS 2

// buckets: node>>6 -> 782 buckets of 64 nodes
#define DB 64
#define NDB 782
#define BCAP 1536        // mean 1024, sigma 32 -> +16 sigma headroom
#define EPB 2048         // edges per scatter block (8/thread) -> 391 blocks
#define NB_EDGE ((N_EDGES + EPB - 1) / EPB)
#define CSTRIDE 32       // cur_d padded: 1 counter per 128B line (L2 same-line atomic serialization)

// ---------------- workspace layout (4-byte units) ----------------
#define OFF_CURD 0        // int[NDB*CSTRIDE=25024] dst-bucket cursors (zeroed by init)
#define OFF_DEGS 25024    // int[50000] src out-degree (global fire-and-forget atomics)
#define OFF_RBD  75024    // int2[50000] (row_beg, deg) packed
#define OFF_NDST 175024   // f32[50000]
#define OFF_NSRC 225024   // f32[50000]
#define OFF_W1T  275024   // bf16[64*256] transposed W1 = 8192 words
#define OFF_DPK  283216   // int[782*1536=1201152] packed (src<<6|dst&63)
#define OFF_CSR  1484368  // int[1201152] csr src ids
#define OFF_HB   2685520  // bf16[50000*64] = 1600000 dwords (UN-normed x@W1)
#define OFF_H2   4285520  // f32[100000]

typedef __attribute__((ext_vector_type(8))) short bf16x8;
typedef __attribute__((ext_vector_type(8))) short short8;
typedef __attribute__((ext_vector_type(4))) float f32x4;

static __device__ __forceinline__ unsigned short f2bf(float f) {
    union { float f; unsigned int u; } v; v.f = f;
    return (unsigned short)((v.u + 0x8000u) >> 16);
}
static __device__ __forceinline__ unsigned int pk2bf(float f0, float f1) {
    union { float f; unsigned int u; } a, b; a.f = f0; b.f = f1;
    return __builtin_amdgcn_perm(b.u + 0x8000u, a.u + 0x8000u, 0x07060302u);
}
static __device__ __forceinline__ float bflo(unsigned int u) {
    union { unsigned int x; float f; } v; v.x = u << 16; return v.f;
}
static __device__ __forceinline__ float bfhi(unsigned int u) {
    union { unsigned int x; float f; } v; v.x = u & 0xffff0000u; return v.f;
}

// K0: zero cur_d + deg_src, W1 -> W1T bf16
#define INIT_CUR (NDB * CSTRIDE)
#define INIT_N (INIT_CUR + N_NODES + NFEAT * NHID)
__global__ __launch_bounds__(256) void init_kernel(const float* __restrict__ W1,
                                                   int* __restrict__ cur_d,
                                                   int* __restrict__ deg_src,
                                                   unsigned short* __restrict__ w1t) {
    int g = blockIdx.x * 256 + threadIdx.x;
    if (g < INIT_CUR) {
        cur_d[g] = 0;
    } else if (g < INIT_CUR + N_NODES) {
        deg_src[g - INIT_CUR] = 0;
    } else if (g < INIT_N) {
        int idx = g - INIT_CUR - N_NODES;
        int k = idx >> 6, n = idx & 63;
        w1t[n * NFEAT + k] = f2bf(W1[idx]);
    }
}

// K1: interleaved roles (bid%3==0 -> scatter, else gemm); 391+782=1173 blocks.
//  scatter: partition edges into dst-buckets (packed src<<6|dstlow);
//           out-degree via global no-return atomics on deg_src.
//  gemm:    hb = bf16(x @ W1T) — LDS-FREE: A fragment (8 contiguous k) loaded
//           as 2x float4 straight from x; B fragment straight from w1t (L1).
struct SgShared { int hd[NDB], bd[NDB], cd[NDB]; };   // 9.4 KB
__global__ __launch_bounds__(256) void sg_kernel(const int* __restrict__ src,
                                                 const int* __restrict__ dst,
                                                 const float* __restrict__ x,
                                                 const unsigned short* __restrict__ w1t,
                                                 int* __restrict__ cur_d,
                                                 int* __restrict__ deg_src,
                                                 int* __restrict__ dpk,
                                                 unsigned short* __restrict__ hb) {
    __shared__ SgShared su;
    int t = threadIdx.x;
    int bid = blockIdx.x;
    if (bid % 3 == 0) {
        // ---- scatter role ----
        int eb = bid / 3;
        for (int i = t; i < NDB; i += 256) { su.hd[i] = 0; su.cd[i] = 0; }
        __syncthreads();
        int base = eb * EPB;
        int ls[8], ld[8];
#pragma unroll
        for (int i = 0; i < 8; ++i) {
            int e = base + t + i * 256;
            ls[i] = (e < N_EDGES) ? src[e] : -1;
            ld[i] = (e < N_EDGES) ? dst[e] : -1;
            if (ld[i] >= 0) {
                atomicAdd(&su.hd[ld[i] >> 6], 1);
                atomicAdd(&deg_src[ls[i]], 1);   // no return -> fire-and-forget
            }
        }
        __syncthreads();
        for (int i = t; i < NDB; i += 256)
            if (su.hd[i]) su.bd[i] = atomicAdd(&cur_d[i * CSTRIDE], su.hd[i]);
        __syncthreads();
#pragma unroll
        for (int i = 0; i < 8; ++i) {
            if (ld[i] >= 0) {
                int bin = ld[i] >> 6;
                int pos = su.bd[bin] + atomicAdd(&su.cd[bin], 1);
                dpk[bin * BCAP + pos] = (ls[i] << 6) | (ld[i] & 63);
            }
        }
    } else {
        // ---- gemm role: LDS-free, direct-fragment MFMA ----
        const int b = (bid / 3) * 2 + (bid % 3) - 1;   // 0..781
        const int row0 = b * 64;
        const int w = t >> 6;
        const int l = t & 63;
        const int m = l & 15;
        const int q = l >> 4;
        int grow = row0 + w * 16 + m;
        const float* xr = &x[(size_t)((grow < N_NODES) ? grow : 0) * NFEAT];
        f32x4 acc[4] = {{0.f, 0.f, 0.f, 0.f}, {0.f, 0.f, 0.f, 0.f},
                        {0.f, 0.f, 0.f, 0.f}, {0.f, 0.f, 0.f, 0.f}};
#pragma unroll
        for (int c8 = 0; c8 < 8; ++c8) {
            int k0 = c8 * 32 + q * 8;
            float4 av0 = *(const float4*)(xr + k0);
            float4 av1 = *(const float4*)(xr + k0 + 4);
            union { bf16x8 v; unsigned int u[4]; } a;
            a.u[0] = pk2bf(av0.x, av0.y);
            a.u[1] = pk2bf(av0.z, av0.w);
            a.u[2] = pk2bf(av1.x, av1.y);
            a.u[3] = pk2bf(av1.z, av1.w);
#pragma unroll
            for (int ct = 0; ct < 4; ++ct) {
                bf16x8 bb = *(const bf16x8*)(&w1t[(ct * 16 + m) * NFEAT + k0]);
                acc[ct] = __builtin_amdgcn_mfma_f32_16x16x32_bf16(a.v, bb, acc[ct], 0, 0, 0);
            }
        }
#pragma unroll
        for (int reg = 0; reg < 4; ++reg) {
            int r = row0 + w * 16 + q * 4 + reg;
            if (r < N_NODES) {
#pragma unroll
                for (int ct = 0; ct < 4; ++ct)
                    hb[(size_t)r * NHID + ct * 16 + m] = f2bf(acc[ct][reg]);
            }
        }
    }
}

// K2: dfin — CSR build + norm_dst + norm_src (from deg_src), one block per bucket
struct FinShared { int ebuf[BCAP]; int hist4[256]; int hist[64]; int seg[64]; int cur[64]; };
__global__ __launch_bounds__(256) void fin_kernel(const int* __restrict__ cur_d,
                                                  const int* __restrict__ deg_src,
                                                  const int* __restrict__ dpk,
                                                  int2* __restrict__ rbdeg,
                                                  float* __restrict__ norm_dst,
                                                  float* __restrict__ norm_src,
                                                  int* __restrict__ csr) {
    __shared__ FinShared su;
    int t = threadIdx.x;
    int b = blockIdx.x;
    int cnt = cur_d[b * CSTRIDE];
    int base = b * BCAP;
    if (t < 64) { su.hist[t] = 0; su.cur[t] = 0; }
    su.hist4[t] = 0;
    for (int j = t; j < cnt; j += 256) su.ebuf[j] = dpk[base + j];
    __syncthreads();
    int sub = (t & 3) * 64;
    for (int j = t; j < cnt; j += 256) atomicAdd(&su.hist4[sub + (su.ebuf[j] & 63)], 1);
    __syncthreads();
    if (t < 64) {
        int v = su.hist4[t] + su.hist4[64 + t] + su.hist4[128 + t] + su.hist4[192 + t];
        su.hist[t] = v;
        su.seg[t] = v;
    }
    __syncthreads();
#pragma unroll
    for (int off = 1; off < 64; off <<= 1) {
        int xv = 0;
        if (t < 64 && t >= off) xv = su.seg[t - off];
        __syncthreads();
        if (t < 64) su.seg[t] += xv;
        __syncthreads();
    }
    if (t < 64) {
        int v = su.hist[t];
        int excl = su.seg[t] - v;
        int gid = b * 64 + t;
        if (gid < N_NODES) {
            rbdeg[gid] = make_int2(base + excl, v);
            norm_dst[gid] = rsqrtf(fmaxf((float)v, 1.0f));
            norm_src[gid] = rsqrtf(fmaxf((float)deg_src[gid], 1.0f));
        }
        su.seg[t] = excl;
    }
    __syncthreads();
    for (int j = t; j < cnt; j += 256) {
        int p = su.ebuf[j];
        int dlow = p & 63;
        int pos = base + su.seg[dlow] + atomicAdd(&su.cur[dlow], 1);
        csr[pos] = ((unsigned)p) >> 6;
    }
}

// K3: fused layer1, node-major, register accumulation, 32 edges in flight
// per wave (4 predicated dwordx4 x 8 edge-slots). lane = e8*8 + fg.
// hb is UN-normed -> apply norm_src[s] per edge via fmaf.
__global__ __launch_bounds__(256) void fused1_kernel(const int2* __restrict__ rbdeg,
                                                     const int* __restrict__ csr,
                                                     const unsigned short* __restrict__ hb,
                                                     const float* __restrict__ norm_dst,
                                                     const float* __restrict__ norm_src,
                                                     const float* __restrict__ b1,
                                                     const float* __restrict__ W2,
                                                     float* __restrict__ h2) {
    int gtid = blockIdx.x * blockDim.x + threadIdx.x;
    int node = gtid >> 6;
    int lane = gtid & 63;
    if (node >= N_NODES) return;
    int e8 = lane >> 3, fg = lane & 7;
    int2 rd = rbdeg[node];
    int beg = rd.x;
    int end = beg + rd.y;
    float a0 = 0.f, a1 = 0.f, a2 = 0.f, a3 = 0.f, a4 = 0.f, a5 = 0.f, a6 = 0.f, a7 = 0.f;
    for (int j = beg; j < end; j += 32) {
        int j0 = j + e8, j1 = j0 + 8, j2 = j0 + 16, j3 = j0 + 24;
        uint4 u0 = make_uint4(0u, 0u, 0u, 0u), u1 = make_uint4(0u, 0u, 0u, 0u);
        uint4 u2 = make_uint4(0u, 0u, 0u, 0u), u3 = make_uint4(0u, 0u, 0u, 0u);
        float ns0 = 0.f, ns1 = 0.f, ns2 = 0.f, ns3 = 0.f;
        if (j0 < end) {
            int s = csr[j0];
            ns0 = norm_src[s];
            u0 = *(const uint4*)(&hb[(size_t)s * NHID + fg * 8]);
        }
        if (j1 < end) {
            int s = csr[j1];
            ns1 = norm_src[s];
            u1 = *(const uint4*)(&hb[(size_t)s * NHID + fg * 8]);
        }
        if (j2 < end) {
            int s = csr[j2];
            ns2 = norm_src[s];
            u2 = *(const uint4*)(&hb[(size_t)s * NHID + fg * 8]);
        }
        if (j3 < end) {
            int s = csr[j3];
            ns3 = norm_src[s];
            u3 = *(const uint4*)(&hb[(size_t)s * NHID + fg * 8]);
        }
        a0 = fmaf(ns0, bflo(u0.x), fmaf(ns1, bflo(u1.x), fmaf(ns2, bflo(u2.x), fmaf(ns3, bflo(u3.x), a0))));
        a1 = fmaf(ns0, bfhi(u0.x), fmaf(ns1, bfhi(u1.x), fmaf(ns2, bfhi(u2.x), fmaf(ns3, bfhi(u3.x), a1))));
        a2 = fmaf(ns0, bflo(u0.y), fmaf(ns1, bflo(u1.y), fmaf(ns2, bflo(u2.y), fmaf(ns3, bflo(u3.y), a2))));
        a3 = fmaf(ns0, bfhi(u0.y), fmaf(ns1, bfhi(u1.y), fmaf(ns2, bfhi(u2.y), fmaf(ns3, bfhi(u3.y), a3))));
        a4 = fmaf(ns0, bflo(u0.z), fmaf(ns1, bflo(u1.z), fmaf(ns2, bflo(u2.z), fmaf(ns3, bflo(u3.z), a4))));
        a5 = fmaf(ns0, bfhi(u0.z), fmaf(ns1, bfhi(u1.z), fmaf(ns2, bfhi(u2.z), fmaf(ns3, bfhi(u3.z), a5))));
        a6 = fmaf(ns0, bflo(u0.w), fmaf(ns1, bflo(u1.w), fmaf(ns2, bflo(u2.w), fmaf(ns3, bflo(u3.w), a6))));
        a7 = fmaf(ns0, bfhi(u0.w), fmaf(ns1, bfhi(u1.w), fmaf(ns2, bfhi(u2.w), fmaf(ns3, bfhi(u3.w), a7))));
    }
#pragma unroll
    for (int off = 8; off <= 32; off <<= 1) {
        a0 += __shfl_xor(a0, off, 64);
        a1 += __shfl_xor(a1, off, 64);
        a2 += __shfl_xor(a2, off, 64);
        a3 += __shfl_xor(a3, off, 64);
        a4 += __shfl_xor(a4, off, 64);
        a5 += __shfl_xor(a5, off, 64);
        a6 += __shfl_xor(a6, off, 64);
        a7 += __shfl_xor(a7, off, 64);
    }
    float nd = norm_dst[node], ns = norm_src[node];
    float4 bv0 = *(const float4*)(&b1[fg * 8]);
    float4 bv1 = *(const float4*)(&b1[fg * 8 + 4]);
    float4 w0 = *(const float4*)(&W2[fg * 16 + 0]);
    float4 w1 = *(const float4*)(&W2[fg * 16 + 4]);
    float4 w2v = *(const float4*)(&W2[fg * 16 + 8]);
    float4 w3 = *(const float4*)(&W2[fg * 16 + 12]);
    float h0 = fmaxf(fmaf(a0, nd, bv0.x), 0.f) * ns;
    float h1 = fmaxf(fmaf(a1, nd, bv0.y), 0.f) * ns;
    float h2f = fmaxf(fmaf(a2, nd, bv0.z), 0.f) * ns;
    float h3 = fmaxf(fmaf(a3, nd, bv0.w), 0.f) * ns;
    float h4 = fmaxf(fmaf(a4, nd, bv1.x), 0.f) * ns;
    float h5 = fmaxf(fmaf(a5, nd, bv1.y), 0.f) * ns;
    float h6 = fmaxf(fmaf(a6, nd, bv1.z), 0.f) * ns;
    float h7 = fmaxf(fmaf(a7, nd, bv1.w), 0.f) * ns;
    float p0 = h0 * w0.x + h1 * w0.z + h2f * w1.x + h3 * w1.z +
               h4 * w2v.x + h5 * w2v.z + h6 * w3.x + h7 * w3.z;
    float p1 = h0 * w0.y + h1 * w0.w + h2f * w1.y + h3 * w1.w +
               h4 * w2v.y + h5 * w2v.w + h6 * w3.y + h7 * w3.w;
#pragma unroll
    for (int off = 1; off <= 4; off <<= 1) {
        p0 += __shfl_xor(p0, off, 64);
        p1 += __shfl_xor(p1, off, 64);
    }
    if (lane == 0) *(float2*)(&h2[node * 2]) = make_float2(p0, p1);
}

// K4: fused layer2: one 16-lane group per node, shfl reduce, log_softmax.
__global__ __launch_bounds__(256) void fused2_kernel(const int2* __restrict__ rbdeg,
                                                     const int* __restrict__ csr,
                                                     const float* __restrict__ h2,
                                                     const float* __restrict__ norm_dst,
                                                     const float* __restrict__ b2,
                                                     float* __restrict__ out) {
    int gtid = blockIdx.x * blockDim.x + threadIdx.x;
    int n = gtid >> 4;
    int l16 = gtid & 15;
    if (n >= N_NODES) return;
    int2 rd = rbdeg[n];
    int beg = rd.x, end = rd.x + rd.y;
    float s0 = 0.f, s1 = 0.f;
    for (int j = beg + l16; j < end; j += 16) {
        float2 v = *(const float2*)(&h2[csr[j] * 2]);
        s0 += v.x;
        s1 += v.y;
    }
#pragma unroll
    for (int off = 1; off <= 8; off <<= 1) {
        s0 += __shfl_xor(s0, off, 16);
        s1 += __shfl_xor(s1, off, 16);
    }
    if (l16 == 0) {
        float nd = norm_dst[n];
        float l0 = fmaf(s0, nd, b2[0]);
        float l1 = fmaf(s1, nd, b2[1]);
        float m = fmaxf(l0, l1);
        float lse = m + logf(expf(l0 - m) + expf(l1 - m));
        *(float2*)(&out[n * 2]) = make_float2(l0 - lse, l1 - lse);
    }
}

extern "C" void kernel_launch(void* const* d_in, const int* in_sizes, int n_in,
                              void* d_out, int out_size, void* d_ws, size_t ws_size,
                              hipStream_t stream) {
    const float* x  = (const float*)d_in[0];
    const int* src  = (const int*)d_in[1];
    const int* dst  = (const int*)d_in[2];
    const float* W1 = (const float*)d_in[3];
    const float* b1 = (const float*)d_in[4];
    const float* W2 = (const float*)d_in[5];
    const float* b2 = (const float*)d_in[6];
    float* out = (float*)d_out;
    float* ws  = (float*)d_ws;
    int*   wsi = (int*)d_ws;

    int*   cur_d    = wsi + OFF_CURD;
    int*   deg_src  = wsi + OFF_DEGS;
    int2*  rbdeg    = (int2*)(wsi + OFF_RBD);
    float* norm_dst = ws + OFF_NDST;
    float* norm_src = ws + OFF_NSRC;
    unsigned short* w1t = (unsigned short*)(wsi + OFF_W1T);
    int*   dpk      = wsi + OFF_DPK;
    int*   csr      = wsi + OFF_CSR;
    unsigned short* hb = (unsigned short*)(wsi + OFF_HB);
    float* h2       = ws + OFF_H2;

    init_kernel<<<(INIT_N + 255) / 256, 256, 0, stream>>>(W1, cur_d, deg_src, w1t);
    sg_kernel<<<NB_EDGE + NDB, 256, 0, stream>>>(src, dst, x, w1t, cur_d, deg_src, dpk, hb);
    fin_kernel<<<NDB, 256, 0, stream>>>(cur_d, deg_src, dpk, rbdeg, norm_dst, norm_src, csr);
    {
        long long threads = (long long)N_NODES * 64;
        fused1_kernel<<<(int)((threads + 255) / 256), 256, 0, stream>>>(
            rbdeg, csr, hb, norm_dst, norm_src, b1, W2, h2);
    }
    {
        long long threads = (long long)N_NODES * 16;
        fused2_kernel<<<(int)((threads + 255) / 256), 256, 0, stream>>>(
            rbdeg, csr, h2, norm_dst, b2, out);
    }
}

// Round 2
// 178.382 us; speedup vs baseline: 1.0697x; 1.0697x over previous
//
#include <hip/hip_runtime.h>
#include <math.h>

#define N_NODES 50000
#define N_EDGES 800000
#define NFEAT 256
#define NHID 64
#define NCLASS 2

// buckets: node>>6 -> 782 buckets of 64 nodes
#define DB 64
#define NDB 782
#define BCAP 1536        // mean 1024, sigma 32 -> +16 sigma headroom
#define EPB 2048         // edges per scatter block (8/thread) -> 391 blocks
#define NB_EDGE ((N_EDGES + EPB - 1) / EPB)
#define CSTRIDE 32       // cursors padded: 1 counter per 128B line (L2 slice parallelism)

// ---------------- workspace layout (4-byte units) ----------------
#define OFF_CURD 0        // int[NDB*CSTRIDE=25024] dst-bucket cursors
#define OFF_CURS 25024    // int[NDB*CSTRIDE=25024] src-bucket cursors
#define OFF_RBD  50048    // int2[50000] (row_beg, deg)
#define OFF_NDST 150048   // f32[50000]
#define OFF_NSRC 200048   // f32[50000]
#define OFF_W1T  250048   // bf16[64*256] = 8192 words
#define OFF_DPK  258240   // int[782*1536=1201152] packed (src<<6|dst&63); csr aliases this
#define OFF_SV6  1459392  // uchar[1201152] (src&63) by src>>6 = 300288 words
#define OFF_HB   1759680  // bf16[50000*64] = 1600000 dwords (UN-normed x@W1)
#define OFF_H2   3359680  // f32[100000]

typedef __attribute__((ext_vector_type(8))) short bf16x8;
typedef __attribute__((ext_vector_type(8))) short short8;
typedef __attribute__((ext_vector_type(4))) float f32x4;

static __device__ __forceinline__ unsigned short f2bf(float f) {
    union { float f; unsigned int u; } v; v.f = f;
    return (unsigned short)((v.u + 0x8000u) >> 16);
}
static __device__ __forceinline__ unsigned int pk2bf(float f0, float f1) {
    union { float f; unsigned int u; } a, b; a.f = f0; b.f = f1;
    return __builtin_amdgcn_perm(b.u + 0x8000u, a.u + 0x8000u, 0x07060302u);
}
static __device__ __forceinline__ float bflo(unsigned int u) {
    union { unsigned int x; float f; } v; v.x = u << 16; return v.f;
}
static __device__ __forceinline__ float bfhi(unsigned int u) {
    union { unsigned int x; float f; } v; v.x = u & 0xffff0000u; return v.f;
}

// K0: zero cursor arrays (cur_d + cur_s contiguous), W1 -> W1T bf16
#define INIT_CUR (2 * NDB * CSTRIDE)
#define INIT_N (INIT_CUR + NFEAT * NHID)
__global__ __launch_bounds__(256) void init_kernel(const float* __restrict__ W1,
                                                   int* __restrict__ cursors,
                                                   unsigned short* __restrict__ w1t) {
    int g = blockIdx.x * 256 + threadIdx.x;
    if (g < INIT_CUR) {
        cursors[g] = 0;
    } else if (g < INIT_N) {
        int idx = g - INIT_CUR;
        int k = idx >> 6, n = idx & 63;
        w1t[n * NFEAT + k] = f2bf(W1[idx]);
    }
}

// K1: interleaved roles (bid%3==0 -> scatter, else gemm); 391+782=1173 blocks.
//  scatter: partition edges into dst-buckets (packed src<<6|dstlow) AND
//           src-buckets (src&63 bytes, for out-degree) -- LDS atomics only;
//           global degree atomics proved 26MB of coherence write traffic (R1).
//  gemm:    hb = bf16(x @ W1T) -- LDS-FREE: A fragment (8 contiguous k) loaded
//           as 2x float4 straight from x; B fragment straight from w1t (L1).
struct SgShared { int hd[NDB], bd[NDB], cd[NDB], hs[NDB], bs[NDB], cs[NDB]; };  // 18.8 KB
__global__ __launch_bounds__(256) void sg_kernel(const int* __restrict__ src,
                                                 const int* __restrict__ dst,
                                                 const float* __restrict__ x,
                                                 const unsigned short* __restrict__ w1t,
                                                 int* __restrict__ cur_d,
                                                 int* __restrict__ cur_s,
                                                 int* __restrict__ dpk,
                                                 unsigned char* __restrict__ sv6,
                                                 unsigned short* __restrict__ hb) {
    __shared__ SgShared su;
    int t = threadIdx.x;
    int bid = blockIdx.x;
    if (bid % 3 == 0) {
        // ---- scatter role ----
        int eb = bid / 3;
        for (int i = t; i < NDB; i += 256) { su.hd[i] = 0; su.cd[i] = 0; su.hs[i] = 0; su.cs[i] = 0; }
        __syncthreads();
        int base = eb * EPB;
        int ls[8], ld[8];
#pragma unroll
        for (int i = 0; i < 8; ++i) {
            int e = base + t + i * 256;
            ls[i] = (e < N_EDGES) ? src[e] : -1;
            ld[i] = (e < N_EDGES) ? dst[e] : -1;
            if (ld[i] >= 0) {
                atomicAdd(&su.hd[ld[i] >> 6], 1);
                atomicAdd(&su.hs[ls[i] >> 6], 1);
            }
        }
        __syncthreads();
        for (int i = t; i < NDB; i += 256) {
            if (su.hd[i]) su.bd[i] = atomicAdd(&cur_d[i * CSTRIDE], su.hd[i]);
            if (su.hs[i]) su.bs[i] = atomicAdd(&cur_s[i * CSTRIDE], su.hs[i]);
        }
        __syncthreads();
#pragma unroll
        for (int i = 0; i < 8; ++i) {
            if (ld[i] >= 0) {
                int bin = ld[i] >> 6;
                int pos = su.bd[bin] + atomicAdd(&su.cd[bin], 1);
                dpk[bin * BCAP + pos] = (ls[i] << 6) | (ld[i] & 63);
                int sbin = ls[i] >> 6;
                int spos = su.bs[sbin] + atomicAdd(&su.cs[sbin], 1);
                sv6[sbin * BCAP + spos] = (unsigned char)(ls[i] & 63);
            }
        }
    } else {
        // ---- gemm role: LDS-free, direct-fragment MFMA ----
        const int b = (bid / 3) * 2 + (bid % 3) - 1;   // 0..781
        const int row0 = b * 64;
        const int w = t >> 6;
        const int l = t & 63;
        const int m = l & 15;
        const int q = l >> 4;
        int grow = row0 + w * 16 + m;
        const float* xr = &x[(size_t)((grow < N_NODES) ? grow : 0) * NFEAT];
        f32x4 acc[4] = {{0.f, 0.f, 0.f, 0.f}, {0.f, 0.f, 0.f, 0.f},
                        {0.f, 0.f, 0.f, 0.f}, {0.f, 0.f, 0.f, 0.f}};
#pragma unroll
        for (int c8 = 0; c8 < 8; ++c8) {
            int k0 = c8 * 32 + q * 8;
            float4 av0 = *(const float4*)(xr + k0);
            float4 av1 = *(const float4*)(xr + k0 + 4);
            union { bf16x8 v; unsigned int u[4]; } a;
            a.u[0] = pk2bf(av0.x, av0.y);
            a.u[1] = pk2bf(av0.z, av0.w);
            a.u[2] = pk2bf(av1.x, av1.y);
            a.u[3] = pk2bf(av1.z, av1.w);
#pragma unroll
            for (int ct = 0; ct < 4; ++ct) {
                bf16x8 bb = *(const bf16x8*)(&w1t[(ct * 16 + m) * NFEAT + k0]);
                acc[ct] = __builtin_amdgcn_mfma_f32_16x16x32_bf16(a.v, bb, acc[ct], 0, 0, 0);
            }
        }
#pragma unroll
        for (int reg = 0; reg < 4; ++reg) {
            int r = row0 + w * 16 + q * 4 + reg;
            if (r < N_NODES) {
#pragma unroll
                for (int ct = 0; ct < 4; ++ct)
                    hb[(size_t)r * NHID + ct * 16 + m] = f2bf(acc[ct][reg]);
            }
        }
    }
}

// K2: two roles (both depend on K1's scatter):
//  role 0: sfin -- out-degree hist from sv6 -> norm_src
//  role 1: dfin -- CSR build (in-place over dpk: bucket staged to LDS first)
//                  + norm_dst/rbdeg
union FinShared {
    struct { int ebuf[BCAP]; int hist4[256]; int hist[64]; int seg[64]; int cur[64]; } d;  // 7.5 KB
    struct { int hist4[256]; } s;
};
__global__ __launch_bounds__(256) void fin_kernel(const int* __restrict__ cur_d,
                                                  const int* __restrict__ cur_s,
                                                  const int* __restrict__ dpk,
                                                  const unsigned char* __restrict__ sv6,
                                                  int2* __restrict__ rbdeg,
                                                  float* __restrict__ norm_dst,
                                                  float* __restrict__ norm_src,
                                                  int* __restrict__ csr) {
    __shared__ FinShared su;
    int t = threadIdx.x;
    int role = blockIdx.x & 1;
    int b = blockIdx.x >> 1;

    if (role == 0) {
        // ---- sfin ----
        su.s.hist4[t] = 0;
        __syncthreads();
        int cnt = cur_s[b * CSTRIDE];
        int base = b * BCAP;
        int sub = (t & 3) * 64;
        for (int j = t; j < cnt; j += 256) atomicAdd(&su.s.hist4[sub + sv6[base + j]], 1);
        __syncthreads();
        if (t < 64) {
            int gid = b * 64 + t;
            if (gid < N_NODES) {
                int v = su.s.hist4[t] + su.s.hist4[64 + t] + su.s.hist4[128 + t] + su.s.hist4[192 + t];
                norm_src[gid] = rsqrtf(fmaxf((float)v, 1.0f));
            }
        }
    } else {
        // ---- dfin ----
        int cnt = cur_d[b * CSTRIDE];
        int base = b * BCAP;
        if (t < 64) { su.d.hist[t] = 0; su.d.cur[t] = 0; }
        su.d.hist4[t] = 0;
        for (int j = t; j < cnt; j += 256) su.d.ebuf[j] = dpk[base + j];
        __syncthreads();
        int sub = (t & 3) * 64;
        for (int j = t; j < cnt; j += 256) atomicAdd(&su.d.hist4[sub + (su.d.ebuf[j] & 63)], 1);
        __syncthreads();
        if (t < 64) {
            int v = su.d.hist4[t] + su.d.hist4[64 + t] + su.d.hist4[128 + t] + su.d.hist4[192 + t];
            su.d.hist[t] = v;
            su.d.seg[t] = v;
        }
        __syncthreads();
#pragma unroll
        for (int off = 1; off < 64; off <<= 1) {
            int xv = 0;
            if (t < 64 && t >= off) xv = su.d.seg[t - off];
            __syncthreads();
            if (t < 64) su.d.seg[t] += xv;
            __syncthreads();
        }
        if (t < 64) {
            int v = su.d.hist[t];
            int excl = su.d.seg[t] - v;
            int gid = b * 64 + t;
            if (gid < N_NODES) {
                rbdeg[gid] = make_int2(base + excl, v);
                norm_dst[gid] = rsqrtf(fmaxf((float)v, 1.0f));
            }
            su.d.seg[t] = excl;
        }
        __syncthreads();
        // csr aliases dpk: safe, whole bucket already staged in su.d.ebuf and
        // each block owns exactly its bucket's [base, base+BCAP) region.
        for (int j = t; j < cnt; j += 256) {
            int p = su.d.ebuf[j];
            int dlow = p & 63;
            int pos = base + su.d.seg[dlow] + atomicAdd(&su.d.cur[dlow], 1);
            csr[pos] = ((unsigned)p) >> 6;
        }
    }
}

// K3: fused layer1, node-major, register accumulation, 32 edges in flight
// per wave (4 predicated dwordx4 x 8 edge-slots). lane = e8*8 + fg.
// hb is UN-normed -> apply norm_src[s] per edge via fmaf.
__global__ __launch_bounds__(256) void fused1_kernel(const int2* __restrict__ rbdeg,
                                                     const int* __restrict__ csr,
                                                     const unsigned short* __restrict__ hb,
                                                     const float* __restrict__ norm_dst,
                                                     const float* __restrict__ norm_src,
                                                     const float* __restrict__ b1,
                                                     const float* __restrict__ W2,
                                                     float* __restrict__ h2) {
    int gtid = blockIdx.x * blockDim.x + threadIdx.x;
    int node = gtid >> 6;
    int lane = gtid & 63;
    if (node >= N_NODES) return;
    int e8 = lane >> 3, fg = lane & 7;
    int2 rd = rbdeg[node];
    int beg = rd.x;
    int end = beg + rd.y;
    float a0 = 0.f, a1 = 0.f, a2 = 0.f, a3 = 0.f, a4 = 0.f, a5 = 0.f, a6 = 0.f, a7 = 0.f;
    for (int j = beg; j < end; j += 32) {
        int j0 = j + e8, j1 = j0 + 8, j2 = j0 + 16, j3 = j0 + 24;
        uint4 u0 = make_uint4(0u, 0u, 0u, 0u), u1 = make_uint4(0u, 0u, 0u, 0u);
        uint4 u2 = make_uint4(0u, 0u, 0u, 0u), u3 = make_uint4(0u, 0u, 0u, 0u);
        float ns0 = 0.f, ns1 = 0.f, ns2 = 0.f, ns3 = 0.f;
        if (j0 < end) {
            int s = csr[j0];
            ns0 = norm_src[s];
            u0 = *(const uint4*)(&hb[(size_t)s * NHID + fg * 8]);
        }
        if (j1 < end) {
            int s = csr[j1];
            ns1 = norm_src[s];
            u1 = *(const uint4*)(&hb[(size_t)s * NHID + fg * 8]);
        }
        if (j2 < end) {
            int s = csr[j2];
            ns2 = norm_src[s];
            u2 = *(const uint4*)(&hb[(size_t)s * NHID + fg * 8]);
        }
        if (j3 < end) {
            int s = csr[j3];
            ns3 = norm_src[s];
            u3 = *(const uint4*)(&hb[(size_t)s * NHID + fg * 8]);
        }
        a0 = fmaf(ns0, bflo(u0.x), fmaf(ns1, bflo(u1.x), fmaf(ns2, bflo(u2.x), fmaf(ns3, bflo(u3.x), a0))));
        a1 = fmaf(ns0, bfhi(u0.x), fmaf(ns1, bfhi(u1.x), fmaf(ns2, bfhi(u2.x), fmaf(ns3, bfhi(u3.x), a1))));
        a2 = fmaf(ns0, bflo(u0.y), fmaf(ns1, bflo(u1.y), fmaf(ns2, bflo(u2.y), fmaf(ns3, bflo(u3.y), a2))));
        a3 = fmaf(ns0, bfhi(u0.y), fmaf(ns1, bfhi(u1.y), fmaf(ns2, bfhi(u2.y), fmaf(ns3, bfhi(u3.y), a3))));
        a4 = fmaf(ns0, bflo(u0.z), fmaf(ns1, bflo(u1.z), fmaf(ns2, bflo(u2.z), fmaf(ns3, bflo(u3.z), a4))));
        a5 = fmaf(ns0, bfhi(u0.z), fmaf(ns1, bfhi(u1.z), fmaf(ns2, bfhi(u2.z), fmaf(ns3, bfhi(u3.z), a5))));
        a6 = fmaf(ns0, bflo(u0.w), fmaf(ns1, bflo(u1.w), fmaf(ns2, bflo(u2.w), fmaf(ns3, bflo(u3.w), a6))));
        a7 = fmaf(ns0, bfhi(u0.w), fmaf(ns1, bfhi(u1.w), fmaf(ns2, bfhi(u2.w), fmaf(ns3, bfhi(u3.w), a7))));
    }
#pragma unroll
    for (int off = 8; off <= 32; off <<= 1) {
        a0 += __shfl_xor(a0, off, 64);
        a1 += __shfl_xor(a1, off, 64);
        a2 += __shfl_xor(a2, off, 64);
        a3 += __shfl_xor(a3, off, 64);
        a4 += __shfl_xor(a4, off, 64);
        a5 += __shfl_xor(a5, off, 64);
        a6 += __shfl_xor(a6, off, 64);
        a7 += __shfl_xor(a7, off, 64);
    }
    float nd = norm_dst[node], ns = norm_src[node];
    float4 bv0 = *(const float4*)(&b1[fg * 8]);
    float4 bv1 = *(const float4*)(&b1[fg * 8 + 4]);
    float4 w0 = *(const float4*)(&W2[fg * 16 + 0]);
    float4 w1 = *(const float4*)(&W2[fg * 16 + 4]);
    float4 w2v = *(const float4*)(&W2[fg * 16 + 8]);
    float4 w3 = *(const float4*)(&W2[fg * 16 + 12]);
    float h0 = fmaxf(fmaf(a0, nd, bv0.x), 0.f) * ns;
    float h1 = fmaxf(fmaf(a1, nd, bv0.y), 0.f) * ns;
    float h2f = fmaxf(fmaf(a2, nd, bv0.z), 0.f) * ns;
    float h3 = fmaxf(fmaf(a3, nd, bv0.w), 0.f) * ns;
    float h4 = fmaxf(fmaf(a4, nd, bv1.x), 0.f) * ns;
    float h5 = fmaxf(fmaf(a5, nd, bv1.y), 0.f) * ns;
    float h6 = fmaxf(fmaf(a6, nd, bv1.z), 0.f) * ns;
    float h7 = fmaxf(fmaf(a7, nd, bv1.w), 0.f) * ns;
    float p0 = h0 * w0.x + h1 * w0.z + h2f * w1.x + h3 * w1.z +
               h4 * w2v.x + h5 * w2v.z + h6 * w3.x + h7 * w3.z;
    float p1 = h0 * w0.y + h1 * w0.w + h2f * w1.y + h3 * w1.w +
               h4 * w2v.y + h5 * w2v.w + h6 * w3.y + h7 * w3.w;
#pragma unroll
    for (int off = 1; off <= 4; off <<= 1) {
        p0 += __shfl_xor(p0, off, 64);
        p1 += __shfl_xor(p1, off, 64);
    }
    if (lane == 0) *(float2*)(&h2[node * 2]) = make_float2(p0, p1);
}

// K4: fused layer2: one 16-lane group per node, shfl reduce, log_softmax.
__global__ __launch_bounds__(256) void fused2_kernel(const int2* __restrict__ rbdeg,
                                                     const int* __restrict__ csr,
                                                     const float* __restrict__ h2,
                                                     const float* __restrict__ norm_dst,
                                                     const float* __restrict__ b2,
                                                     float* __restrict__ out) {
    int gtid = blockIdx.x * blockDim.x + threadIdx.x;
    int n = gtid >> 4;
    int l16 = gtid & 15;
    if (n >= N_NODES) return;
    int2 rd = rbdeg[n];
    int beg = rd.x, end = rd.x + rd.y;
    float s0 = 0.f, s1 = 0.f;
    for (int j = beg + l16; j < end; j += 16) {
        float2 v = *(const float2*)(&h2[csr[j] * 2]);
        s0 += v.x;
        s1 += v.y;
    }
#pragma unroll
    for (int off = 1; off <= 8; off <<= 1) {
        s0 += __shfl_xor(s0, off, 16);
        s1 += __shfl_xor(s1, off, 16);
    }
    if (l16 == 0) {
        float nd = norm_dst[n];
        float l0 = fmaf(s0, nd, b2[0]);
        float l1 = fmaf(s1, nd, b2[1]);
        float m = fmaxf(l0, l1);
        float lse = m + logf(expf(l0 - m) + expf(l1 - m));
        *(float2*)(&out[n * 2]) = make_float2(l0 - lse, l1 - lse);
    }
}

extern "C" void kernel_launch(void* const* d_in, const int* in_sizes, int n_in,
                              void* d_out, int out_size, void* d_ws, size_t ws_size,
                              hipStream_t stream) {
    const float* x  = (const float*)d_in[0];
    const int* src  = (const int*)d_in[1];
    const int* dst  = (const int*)d_in[2];
    const float* W1 = (const float*)d_in[3];
    const float* b1 = (const float*)d_in[4];
    const float* W2 = (const float*)d_in[5];
    const float* b2 = (const float*)d_in[6];
    float* out = (float*)d_out;
    float* ws  = (float*)d_ws;
    int*   wsi = (int*)d_ws;

    int*   cur_d    = wsi + OFF_CURD;
    int*   cur_s    = wsi + OFF_CURS;
    int2*  rbdeg    = (int2*)(wsi + OFF_RBD);
    float* norm_dst = ws + OFF_NDST;
    float* norm_src = ws + OFF_NSRC;
    unsigned short* w1t = (unsigned short*)(wsi + OFF_W1T);
    int*   dpk      = wsi + OFF_DPK;
    unsigned char* sv6 = (unsigned char*)(wsi + OFF_SV6);
    int*   csr      = wsi + OFF_DPK;   // alias: dfin rewrites its own bucket in place
    unsigned short* hb = (unsigned short*)(wsi + OFF_HB);
    float* h2       = ws + OFF_H2;

    init_kernel<<<(INIT_N + 255) / 256, 256, 0, stream>>>(W1, cur_d, w1t);
    sg_kernel<<<NB_EDGE * 3, 256, 0, stream>>>(src, dst, x, w1t, cur_d, cur_s, dpk, sv6, hb);
    fin_kernel<<<NDB * 2, 256, 0, stream>>>(cur_d, cur_s, dpk, sv6, rbdeg, norm_dst, norm_src, csr);
    {
        long long threads = (long long)N_NODES * 64;
        fused1_kernel<<<(int)((threads + 255) / 256), 256, 0, stream>>>(
            rbdeg, csr, hb, norm_dst, norm_src, b1, W2, h2);
    }
    {
        long long threads = (long long)N_NODES * 16;
        fused2_kernel<<<(int)((threads + 255) / 256), 256, 0, stream>>>(
            rbdeg, csr, h2, norm_dst, b2, out);
    }
}